// Round 11
// baseline (160.484 us; speedup 1.0000x reference)
//
#include <hip/hip_runtime.h>
#include <stdint.h>

#define M_DIM 8192
#define K_DIM 4096
#define N_DIM 4096
#define KB2 2048  // packed fp4 bytes per row = K_DIM/2

using i32x4 = __attribute__((ext_vector_type(4))) int;
using i32x8 = __attribute__((ext_vector_type(8))) int;
using f32x16 = __attribute__((ext_vector_type(16))) float;

typedef const __attribute__((address_space(1))) void g_void;
typedef __attribute__((address_space(3))) void lds_void;

__device__ __forceinline__ void gload_lds16(const void* g, void* l) {
  // async global->LDS, 16B/lane; LDS dest = wave-uniform base + lane*16
  __builtin_amdgcn_global_load_lds((g_void*)g, (lds_void*)l, 16, 0, 0);
}

__device__ __forceinline__ void barrier_raw() {
  asm volatile("" ::: "memory");
  __builtin_amdgcn_s_barrier();
  asm volatile("" ::: "memory");
}

// fp4 e2m1: 0010 = 1.0 -> +1 = 0x2, -1 = 0xA
__device__ __forceinline__ unsigned code4(float v) {
  return v > 0.f ? 0x2u : (v < 0.f ? 0xAu : 0x0u);
}

// ---- pack x: fp32 [M][K] -> fp4-packed [M][K/2] (8 vals -> 1 dword) ----
__global__ void pack_x4_kernel(const float* __restrict__ in,
                               unsigned* __restrict__ out, long n8) {
  long i0 = (long)blockIdx.x * blockDim.x + threadIdx.x;
  long stride = (long)gridDim.x * blockDim.x;
  for (long i = i0; i < n8; i += stride) {
    const float4* p = reinterpret_cast<const float4*>(in + i * 8);
    float4 x0 = p[0], x1 = p[1];
    unsigned w = code4(x0.x) | (code4(x0.y) << 4) | (code4(x0.z) << 8) |
                 (code4(x0.w) << 12) | (code4(x1.x) << 16) |
                 (code4(x1.y) << 20) | (code4(x1.z) << 24) |
                 (code4(x1.w) << 28);
    out[i] = w;
  }
}

// ---- pack w: fp32 [K][N] -> fp4-packed TRANSPOSED [N][K/2] ----
__global__ void pack_wt4_kernel(const float* __restrict__ w,
                                unsigned* __restrict__ wt4) {
  __shared__ uint8_t tile[64 * 68];  // codes, [n][k]
  int n0 = blockIdx.x * 64;
  int k0 = blockIdx.y * 64;
  int t = threadIdx.x;
#pragma unroll
  for (int i = 0; i < 16; ++i) {
    int flat = t + 256 * i;
    int r = flat >> 6;   // k-local
    int c = flat & 63;   // n-local (coalesced)
    tile[c * 68 + r] = (uint8_t)code4(w[(long)(k0 + r) * N_DIM + n0 + c]);
  }
  __syncthreads();
#pragma unroll
  for (int i = 0; i < 2; ++i) {
    int flat = t + 256 * i;  // 512 dwords out
    int nn = flat >> 3;
    int dk = flat & 7;
    const uint8_t* src = &tile[nn * 68 + dk * 8];
    unsigned word = 0;
#pragma unroll
    for (int e = 0; e < 8; ++e) word |= ((unsigned)src[e]) << (4 * e);
    wt4[(long)(n0 + nn) * (K_DIM / 8) + (k0 >> 3) + dk] = word;
  }
}

// ---- MX-fp4 GEMM, 128x256 tile for 2 async blocks/CU ----
// R10 lesson: 1-block/CU lockstep has ~60% structural stall no intra-wave
// schedule removes (two identical rounds). Fix = occupancy: per-wave output
// 64x64 -> acc 64 VGPR -> ~120 regs/wave -> 4 waves/SIMD -> 2 blocks/CU.
// One block's MFMA covers the other's barrier/read stalls (async, no
// cross-block sync). Within a wave: simple drain-0 lgkm (TLP replaces ILP).
// LDS ring: 3 slots x 24 KB (A 8K + B 16K) = 72 KB/block, 2 blocks = 144K.
// vmcnt ledger: body(t) issues stage(t+2) [3 loads]; end-gate needs t+1
// retired, t+2's 3 in flight -> vmcnt(3). Stage target slot (t+2)%3 =
// (t-1)%3: its reads retired at body(t-1)'s lgkm(0), barrier passed. WAR ok.
__device__ __forceinline__ i32x8 lo8(i32x4 r) {
  return __builtin_shufflevector(r, r, 0, 1, 2, 3, -1, -1, -1, -1);
}

#define SCALE1 0x7f7f7f7f  // E8M0 1.0 in every byte

template <int VM, bool ISSUE, int CUR>
__device__ __forceinline__ void tile_step(
    int t, const uint8_t* __restrict__ Asrc, const uint8_t* __restrict__ Bsrc,
    long offA, long offB0, long offB1, int dstA, int dstB0, int dstB1,
    uint8_t* lds, int aRd, int bRd, f32x16 (&acc)[2][2]) {
  const uint8_t* buf = lds + CUR * 24576;
  constexpr int SN = (CUR + 2) % 3;
  // stage tile t+2 into slot SN
  if (ISSUE) {
    long kn = (long)(t + 2) * 64;
    uint8_t* nbuf = lds + SN * 24576;
    gload_lds16(Asrc + offA + kn, nbuf + dstA);
    gload_lds16(Bsrc + offB0 + kn, nbuf + dstB0);
    gload_lds16(Bsrc + offB1 + kn, nbuf + dstB1);
  }
  i32x4 a[2], b[2];
#pragma unroll
  for (int h = 0; h < 2; ++h) {
    a[0] = *reinterpret_cast<const i32x4*>(buf + aRd + h * 1024);
    a[1] = *reinterpret_cast<const i32x4*>(buf + aRd + 2048 + h * 1024);
    b[0] = *reinterpret_cast<const i32x4*>(buf + bRd + h * 1024);
    b[1] = *reinterpret_cast<const i32x4*>(buf + bRd + 2048 + h * 1024);
    asm volatile("s_waitcnt lgkmcnt(0)" ::: "memory");
    __builtin_amdgcn_sched_barrier(0);
    __builtin_amdgcn_s_setprio(1);
#pragma unroll
    for (int mi = 0; mi < 2; ++mi)
#pragma unroll
      for (int ni = 0; ni < 2; ++ni)
        acc[mi][ni] = __builtin_amdgcn_mfma_scale_f32_32x32x64_f8f6f4(
            lo8(a[mi]), lo8(b[ni]), acc[mi][ni], 4, 4, 0, SCALE1, 0, SCALE1);
    __builtin_amdgcn_s_setprio(0);
  }
  // end-gate: tile t+1 staged for all waves (t+2's 3 loads stay in flight)
  if (VM >= 0) {
    if (VM == 3) asm volatile("s_waitcnt vmcnt(3)" ::: "memory");
    else asm volatile("s_waitcnt vmcnt(0)" ::: "memory");
    barrier_raw();
  }
}

__global__ __launch_bounds__(512, 4) void gemm_fp4_kernel(
    const uint8_t* __restrict__ A, const uint8_t* __restrict__ B,
    float* __restrict__ C) {
  __shared__ __align__(16) uint8_t lds[3 * 24576];  // 72 KiB

  // XCD-aware bijective swizzle: nwg = 1024 = 8 * 128
  int bid = blockIdx.x;
  int wg = (bid & 7) * 128 + (bid >> 3);
  int bm = wg >> 4;  // M/128 = 64
  int bn = wg & 15;  // N/256 = 16

  int tid = threadIdx.x;
  int wid = tid >> 6;
  int lane = tid & 63;
  int wr = wid >> 2;  // 0..1 (M halves of 64 rows)
  int wc = wid & 3;   // 0..3 (N quarters of 64 cols)

  const uint8_t* Asrc = A + (long)bm * 128 * KB2;
  const uint8_t* Bsrc = B + (long)bn * 256 * KB2;

  // staging decomp (sub-tiled [mb][kchunk][row32]): slot s -> mb=s>>7,
  // c=(s>>5)&3, row=s&31. A: s=tid (128 rows). B: s=j*512+tid (256 rows).
  long offA = (long)((tid >> 7) * 32 + (tid & 31)) * KB2 + (((tid >> 5) & 3) << 4);
  long offB0 = offA;              // same decomp on B rows 0..127
  long offB1 = offA + 128L * KB2; // rows 128..255
  int dstA = wid * 1024;
  int dstB0 = 8192 + wid * 1024;
  int dstB1 = 16384 + wid * 1024;

  // frag read bases (linear lane*16, R9-verified): A mb = wr*2+mi,
  // B nb = wc*2+ni; half h adds 1024
  int aRd = (wr * 2) * 2048 + lane * 16;
  int bRd = 8192 + (wc * 2) * 2048 + lane * 16;

  f32x16 acc[2][2] = {};

  // prologue: stage tiles 0,1 (6 loads)
  gload_lds16(Asrc + offA, lds + dstA);
  gload_lds16(Bsrc + offB0, lds + dstB0);
  gload_lds16(Bsrc + offB1, lds + dstB1);
  gload_lds16(Asrc + offA + 64, lds + 24576 + dstA);
  gload_lds16(Bsrc + offB0 + 64, lds + 24576 + dstB0);
  gload_lds16(Bsrc + offB1 + 64, lds + 24576 + dstB1);
  asm volatile("s_waitcnt vmcnt(3)" ::: "memory");  // tile 0 landed
  barrier_raw();

#pragma unroll 1
  for (int tt = 0; tt < 30; tt += 3) {
    tile_step<3, true, 0>(tt, Asrc, Bsrc, offA, offB0, offB1, dstA, dstB0,
                          dstB1, lds, aRd, bRd, acc);
    tile_step<3, true, 1>(tt + 1, Asrc, Bsrc, offA, offB0, offB1, dstA, dstB0,
                          dstB1, lds, aRd, bRd, acc);
    tile_step<3, true, 2>(tt + 2, Asrc, Bsrc, offA, offB0, offB1, dstA, dstB0,
                          dstB1, lds, aRd, bRd, acc);
  }
  tile_step<0, false, 0>(30, Asrc, Bsrc, offA, offB0, offB1, dstA, dstB0,
                         dstB1, lds, aRd, bRd, acc);
  tile_step<-1, false, 1>(31, Asrc, Bsrc, offA, offB0, offB1, dstA, dstB0,
                          dstB1, lds, aRd, bRd, acc);

  // C/D 32x32 layout: col = lane&31, row = (reg&3) + 8*(reg>>2) + 4*(lane>>5)
  long row0 = (long)bm * 128 + wr * 64 + ((lane >> 5) << 2);
  long col0 = (long)bn * 256 + wc * 64 + (lane & 31);
#pragma unroll
  for (int mi = 0; mi < 2; ++mi)
#pragma unroll
    for (int ni = 0; ni < 2; ++ni)
#pragma unroll
      for (int r = 0; r < 16; ++r) {
        long row = row0 + mi * 32 + (r & 3) + ((r >> 2) << 3);
        C[row * N_DIM + col0 + ni * 32] = acc[mi][ni][r];
      }
}

extern "C" void kernel_launch(void* const* d_in, const int* in_sizes, int n_in,
                              void* d_out, int out_size, void* d_ws, size_t ws_size,
                              hipStream_t stream) {
  const float* x = (const float*)d_in[0];
  const float* w = (const float*)d_in[1];
  float* out = (float*)d_out;

  uint8_t* x4 = (uint8_t*)d_ws;                     // 16 MB: fp4 sign(x) [M][K/2]
  uint8_t* w4t = x4 + (size_t)M_DIM * KB2;          // 8 MB: fp4 sign(w)^T [N][K/2]

  pack_x4_kernel<<<2048, 256, 0, stream>>>(x, (unsigned*)x4,
                                           (long)M_DIM * K_DIM / 8);
  pack_wt4_kernel<<<dim3(N_DIM / 64, K_DIM / 64), 256, 0, stream>>>(
      w, (unsigned*)w4t);
  gemm_fp4_kernel<<<1024, 512, 0, stream>>>(x4, w4t, out);
}

// Round 12
// 141.344 us; speedup vs baseline: 1.1354x; 1.1354x over previous
//
#include <hip/hip_runtime.h>
#include <stdint.h>

#define M_DIM 8192
#define K_DIM 4096
#define N_DIM 4096
#define KB2 2048  // packed fp4 bytes per row = K_DIM/2

using i32x4 = __attribute__((ext_vector_type(4))) int;
using i32x8 = __attribute__((ext_vector_type(8))) int;
using f32x16 = __attribute__((ext_vector_type(16))) float;

typedef const __attribute__((address_space(1))) void g_void;
typedef __attribute__((address_space(3))) void lds_void;

__device__ __forceinline__ void gload_lds16(const void* g, void* l) {
  // async global->LDS, 16B/lane; LDS dest = wave-uniform base + lane*16
  __builtin_amdgcn_global_load_lds((g_void*)g, (lds_void*)l, 16, 0, 0);
}

__device__ __forceinline__ void barrier_raw() {
  asm volatile("" ::: "memory");
  __builtin_amdgcn_s_barrier();
  asm volatile("" ::: "memory");
}

// fp4 e2m1: 0010 = 1.0 -> +1 = 0x2, -1 = 0xA
__device__ __forceinline__ unsigned code4(float v) {
  return v > 0.f ? 0x2u : (v < 0.f ? 0xAu : 0x0u);
}

// ---- pack x: fp32 [M][K] -> fp4-packed [M][K/2] (8 vals -> 1 dword) ----
__global__ void pack_x4_kernel(const float* __restrict__ in,
                               unsigned* __restrict__ out, long n8) {
  long i0 = (long)blockIdx.x * blockDim.x + threadIdx.x;
  long stride = (long)gridDim.x * blockDim.x;
  for (long i = i0; i < n8; i += stride) {
    const float4* p = reinterpret_cast<const float4*>(in + i * 8);
    float4 x0 = p[0], x1 = p[1];
    unsigned w = code4(x0.x) | (code4(x0.y) << 4) | (code4(x0.z) << 8) |
                 (code4(x0.w) << 12) | (code4(x1.x) << 16) |
                 (code4(x1.y) << 20) | (code4(x1.z) << 24) |
                 (code4(x1.w) << 28);
    out[i] = w;
  }
}

// ---- pack w: fp32 [K][N] -> fp4-packed TRANSPOSED [N][K/2] ----
__global__ void pack_wt4_kernel(const float* __restrict__ w,
                                unsigned* __restrict__ wt4) {
  __shared__ uint8_t tile[64 * 68];  // codes, [n][k]
  int n0 = blockIdx.x * 64;
  int k0 = blockIdx.y * 64;
  int t = threadIdx.x;
#pragma unroll
  for (int i = 0; i < 16; ++i) {
    int flat = t + 256 * i;
    int r = flat >> 6;   // k-local
    int c = flat & 63;   // n-local (coalesced)
    tile[c * 68 + r] = (uint8_t)code4(w[(long)(k0 + r) * N_DIM + n0 + c]);
  }
  __syncthreads();
#pragma unroll
  for (int i = 0; i < 2; ++i) {
    int flat = t + 256 * i;  // 512 dwords out
    int nn = flat >> 3;
    int dk = flat & 7;
    const uint8_t* src = &tile[nn * 68 + dk * 8];
    unsigned word = 0;
#pragma unroll
    for (int e = 0; e < 8; ++e) word |= ((unsigned)src[e]) << (4 * e);
    wt4[(long)(n0 + nn) * (K_DIM / 8) + (k0 >> 3) + dk] = word;
  }
}

// ---- MX-fp4 GEMM: R9 kernel with ONE change: L2-locality block mapping.
// Theory (R12): staged bytes = 512 MB of L2<-L3 traffic (invisible to
// FETCH_SIZE). R9's map gave each XCD bn-spread 16 -> B set 8 MB > 4 MB L2
// -> thrash. New map: XCD = bid&7 owns a (8bm x 8bn) group; resident 32
// blocks = 4bm x 8bn rectangle -> every B k-slice shared by 4 co-resident
// blocks, every A k-slice by 8; hot set per tile-index = 192 KB << L2.
__device__ __forceinline__ i32x8 lo8(i32x4 r) {
  return __builtin_shufflevector(r, r, 0, 1, 2, 3, -1, -1, -1, -1);
}

#define SCALE1 0x7f7f7f7f  // E8M0 1.0 in every byte

template <int VM, bool ISSUE>
__device__ __forceinline__ void tile_step(
    int t, const uint8_t* __restrict__ Asrc, const uint8_t* __restrict__ Bsrc,
    long off0, long off1, int dstOff, uint8_t* lds, int aRd, int bRd,
    f32x16 (&acc)[4][2]) {
  const uint8_t* buf = lds + (t & 3) * 32768;
  // stage tile t+3 into slot (t+3)&3 (R9-proven WAR ledger)
  if (ISSUE) {
    long kn = (long)(t + 3) * 64;
    uint8_t* nbuf = lds + ((t + 3) & 3) * 32768;
    gload_lds16(Asrc + off0 + kn, nbuf + dstOff);
    gload_lds16(Asrc + off1 + kn, nbuf + 8192 + dstOff);
    gload_lds16(Bsrc + off0 + kn, nbuf + 16384 + dstOff);
    gload_lds16(Bsrc + off1 + kn, nbuf + 24576 + dstOff);
  }
  // all 12 frag reads: h0 first (lgkm(6) retires exactly those)
  i32x4 a0[4], b0[2], a1[4], b1[2];
#pragma unroll
  for (int mi = 0; mi < 4; ++mi)
    a0[mi] = *reinterpret_cast<const i32x4*>(buf + aRd + mi * 2048);
#pragma unroll
  for (int ni = 0; ni < 2; ++ni)
    b0[ni] = *reinterpret_cast<const i32x4*>(buf + bRd + ni * 2048);
#pragma unroll
  for (int mi = 0; mi < 4; ++mi)
    a1[mi] = *reinterpret_cast<const i32x4*>(buf + aRd + mi * 2048 + 1024);
#pragma unroll
  for (int ni = 0; ni < 2; ++ni)
    b1[ni] = *reinterpret_cast<const i32x4*>(buf + bRd + ni * 2048 + 1024);
  asm volatile("s_waitcnt lgkmcnt(6)" ::: "memory");  // h0 ready, h1 in flight
  __builtin_amdgcn_sched_barrier(0);
  __builtin_amdgcn_s_setprio(1);
#pragma unroll
  for (int mi = 0; mi < 4; ++mi)
#pragma unroll
    for (int ni = 0; ni < 2; ++ni)
      acc[mi][ni] = __builtin_amdgcn_mfma_scale_f32_32x32x64_f8f6f4(
          lo8(a0[mi]), lo8(b0[ni]), acc[mi][ni], 4, 4, 0, SCALE1, 0, SCALE1);
  __builtin_amdgcn_s_setprio(0);
  asm volatile("s_waitcnt lgkmcnt(0)" ::: "memory");  // h1 ready
  __builtin_amdgcn_sched_barrier(0);
  __builtin_amdgcn_s_setprio(1);
#pragma unroll
  for (int mi = 0; mi < 4; ++mi)
#pragma unroll
    for (int ni = 0; ni < 2; ++ni)
      acc[mi][ni] = __builtin_amdgcn_mfma_scale_f32_32x32x64_f8f6f4(
          lo8(a1[mi]), lo8(b1[ni]), acc[mi][ni], 4, 4, 0, SCALE1, 0, SCALE1);
  __builtin_amdgcn_s_setprio(0);
  // gate: tile t+1 landed for all waves (vmcnt(8) = tiles t+2,t+3 in flight)
  if (VM >= 0) {
    if (VM == 8) asm volatile("s_waitcnt vmcnt(8)" ::: "memory");
    else if (VM == 4) asm volatile("s_waitcnt vmcnt(4)" ::: "memory");
    else asm volatile("s_waitcnt vmcnt(0)" ::: "memory");
    barrier_raw();
  }
}

__global__ __launch_bounds__(512, 2) void gemm_fp4_kernel(
    const uint8_t* __restrict__ A, const uint8_t* __restrict__ B,
    float* __restrict__ C) {
  __shared__ __align__(16) uint8_t lds[4 * 32768];  // 128 KiB

  // L2-locality XCD mapping (R12): xcd = bid&7 -> (bn-half, bm-group);
  // i = bid>>3 -> (bn-low 3b, bm-low 3b). Bijective over 32bm x 16bn.
  int bid = blockIdx.x;
  int xcd = bid & 7;
  int i = bid >> 3;                       // 0..63
  int bn = (i & 7) + ((xcd & 1) << 3);    // 0..15, spread 8 per XCD
  int bm = (i >> 3) + ((xcd >> 1) << 3);  // 0..31, spread 8 per XCD

  int tid = threadIdx.x;
  int wid = tid >> 6;
  int lane = tid & 63;
  int wr = wid >> 2;  // 0..1 (M)
  int wc = wid & 3;   // 0..3 (N)

  const uint8_t* Asrc = A + (long)bm * 256 * KB2;
  const uint8_t* Bsrc = B + (long)bn * 256 * KB2;

  // staging decomp for slot s = j*512 + tid: mb=s>>7, c=(s>>5)&3, row=s&31
  long off0 = (long)((tid >> 7) * 32 + (tid & 31)) * KB2 + (((tid >> 5) & 3) << 4);
  long off1 = off0 + 128L * KB2;
  int dstOff = wid * 1024;  // wave-uniform; HW adds lane*16

  // frag read bases (linear lane*16): A mb = wr*4 + mi, B nb = wc*2 + ni
  int aRd = (wr * 4) * 2048 + lane * 16;
  int bRd = 16384 + (wc * 2) * 2048 + lane * 16;

  f32x16 acc[4][2] = {};

  // prologue: stage tiles 0,1,2 (12 loads in flight)
#pragma unroll
  for (int t = 0; t < 3; ++t) {
    uint8_t* buf = lds + t * 32768;
    long k0 = (long)t * 64;
    gload_lds16(Asrc + off0 + k0, buf + dstOff);
    gload_lds16(Asrc + off1 + k0, buf + 8192 + dstOff);
    gload_lds16(Bsrc + off0 + k0, buf + 16384 + dstOff);
    gload_lds16(Bsrc + off1 + k0, buf + 24576 + dstOff);
  }
  asm volatile("s_waitcnt vmcnt(8)" ::: "memory");  // tile 0 landed
  barrier_raw();

#pragma unroll 1
  for (int t = 0; t < 29; ++t)
    tile_step<8, true>(t, Asrc, Bsrc, off0, off1, dstOff, lds, aRd, bRd, acc);
  tile_step<4, false>(29, Asrc, Bsrc, off0, off1, dstOff, lds, aRd, bRd, acc);
  tile_step<0, false>(30, Asrc, Bsrc, off0, off1, dstOff, lds, aRd, bRd, acc);
  tile_step<-1, false>(31, Asrc, Bsrc, off0, off1, dstOff, lds, aRd, bRd, acc);

  // C/D 32x32 layout: col = lane&31, row = (reg&3) + 8*(reg>>2) + 4*(lane>>5)
  long row0 = (long)bm * 256 + wr * 128 + ((lane >> 5) << 2);
  long col0 = (long)bn * 256 + wc * 64 + (lane & 31);
#pragma unroll
  for (int mi = 0; mi < 4; ++mi)
#pragma unroll
    for (int ni = 0; ni < 2; ++ni)
#pragma unroll
      for (int r = 0; r < 16; ++r) {
        long row = row0 + mi * 32 + (r & 3) + ((r >> 2) << 3);
        C[row * N_DIM + col0 + ni * 32] = acc[mi][ni][r];
      }
}

extern "C" void kernel_launch(void* const* d_in, const int* in_sizes, int n_in,
                              void* d_out, int out_size, void* d_ws, size_t ws_size,
                              hipStream_t stream) {
  const float* x = (const float*)d_in[0];
  const float* w = (const float*)d_in[1];
  float* out = (float*)d_out;

  uint8_t* x4 = (uint8_t*)d_ws;                     // 16 MB: fp4 sign(x) [M][K/2]
  uint8_t* w4t = x4 + (size_t)M_DIM * KB2;          // 8 MB: fp4 sign(w)^T [N][K/2]

  pack_x4_kernel<<<2048, 256, 0, stream>>>(x, (unsigned*)x4,
                                           (long)M_DIM * K_DIM / 8);
  pack_wt4_kernel<<<dim3(N_DIM / 64, K_DIM / 64), 256, 0, stream>>>(
      w, (unsigned*)w4t);
  gemm_fp4_kernel<<<512, 512, 0, stream>>>(x4, w4t, out);
}

// Round 13
// 140.971 us; speedup vs baseline: 1.1384x; 1.0026x over previous
//
#include <hip/hip_runtime.h>
#include <stdint.h>

#define M_DIM 8192
#define K_DIM 4096
#define N_DIM 4096
#define KB2 2048  // packed fp4 bytes per row = K_DIM/2

using i32x4 = __attribute__((ext_vector_type(4))) int;
using i32x8 = __attribute__((ext_vector_type(8))) int;
using f32x16 = __attribute__((ext_vector_type(16))) float;

typedef const __attribute__((address_space(1))) void g_void;
typedef __attribute__((address_space(3))) void lds_void;

__device__ __forceinline__ void gload_lds16(const void* g, void* l) {
  __builtin_amdgcn_global_load_lds((g_void*)g, (lds_void*)l, 16, 0, 0);
}

__device__ __forceinline__ void barrier_raw() {
  asm volatile("" ::: "memory");
  __builtin_amdgcn_s_barrier();
  asm volatile("" ::: "memory");
}

// fp4 e2m1: 0010 = 1.0 -> +1 = 0x2, -1 = 0xA
__device__ __forceinline__ unsigned code4(float v) {
  return v > 0.f ? 0x2u : (v < 0.f ? 0xAu : 0x0u);
}

// ---- pack x: fp32 [M][K] -> fp4-packed [M][K/2] ----
__global__ void pack_x4_kernel(const float* __restrict__ in,
                               unsigned* __restrict__ out, long n8) {
  long i0 = (long)blockIdx.x * blockDim.x + threadIdx.x;
  long stride = (long)gridDim.x * blockDim.x;
  for (long i = i0; i < n8; i += stride) {
    const float4* p = reinterpret_cast<const float4*>(in + i * 8);
    float4 x0 = p[0], x1 = p[1];
    unsigned w = code4(x0.x) | (code4(x0.y) << 4) | (code4(x0.z) << 8) |
                 (code4(x0.w) << 12) | (code4(x1.x) << 16) |
                 (code4(x1.y) << 20) | (code4(x1.z) << 24) |
                 (code4(x1.w) << 28);
    out[i] = w;
  }
}

// ---- pack w: fp32 [K][N] -> fp4-packed TRANSPOSED [N][K/2] ----
__global__ void pack_wt4_kernel(const float* __restrict__ w,
                                unsigned* __restrict__ wt4) {
  __shared__ uint8_t tile[64 * 68];  // codes, [n][k]
  int n0 = blockIdx.x * 64;
  int k0 = blockIdx.y * 64;
  int t = threadIdx.x;
#pragma unroll
  for (int i = 0; i < 16; ++i) {
    int flat = t + 256 * i;
    int r = flat >> 6;
    int c = flat & 63;
    tile[c * 68 + r] = (uint8_t)code4(w[(long)(k0 + r) * N_DIM + n0 + c]);
  }
  __syncthreads();
#pragma unroll
  for (int i = 0; i < 2; ++i) {
    int flat = t + 256 * i;
    int nn = flat >> 3;
    int dk = flat & 7;
    const uint8_t* src = &tile[nn * 68 + dk * 8];
    unsigned word = 0;
#pragma unroll
    for (int e = 0; e < 8; ++e) word |= ((unsigned)src[e]) << (4 * e);
    wt4[(long)(n0 + nn) * (K_DIM / 8) + (k0 >> 3) + dk] = word;
  }
}

// ---- MX-fp4 GEMM, m201-faithful 8-phase schedule (4 phases per BK=128
//      tile). Each phase: {2-4 ds_read_b128 (own operands) -> 1 stage-issue
//      -> [vm gate, P4 only] -> barrier -> lgkm(0) -> setprio(1) -> 4 MFMA
//      -> setprio(0) -> barrier}. Reads drain during the pre-MFMA barrier
//      wait; the 2-barrier rhythm creates the wave role-split T5 needs
//      (m218b). vmcnt(8) once per tile at P4 = tiles t+2,t+3 in flight.
// WAR: slot (t+3)&3=(t-1)&3 first rewritten at t's P1, after t-1's P4
// lgkm(0)+barrier drained all reads of it.
__device__ __forceinline__ i32x8 lo8(i32x4 r) {
  return __builtin_shufflevector(r, r, 0, 1, 2, 3, -1, -1, -1, -1);
}

#define SCALE1 0x7f7f7f7f  // E8M0 1.0 in every byte

#define MFMA4(ACCI)                                                        \
  do {                                                                     \
    asm volatile("s_waitcnt lgkmcnt(0)" ::: "memory");                     \
    __builtin_amdgcn_sched_barrier(0);                                     \
    __builtin_amdgcn_s_setprio(1);                                         \
    acc[ACCI][0] = __builtin_amdgcn_mfma_scale_f32_32x32x64_f8f6f4(        \
        lo8(a[0]), lo8(b[0]), acc[ACCI][0], 4, 4, 0, SCALE1, 0, SCALE1);   \
    acc[ACCI][1] = __builtin_amdgcn_mfma_scale_f32_32x32x64_f8f6f4(        \
        lo8(a[0]), lo8(b[1]), acc[ACCI][1], 4, 4, 0, SCALE1, 0, SCALE1);   \
    acc[ACCI + 1][0] = __builtin_amdgcn_mfma_scale_f32_32x32x64_f8f6f4(    \
        lo8(a[1]), lo8(b[0]), acc[ACCI + 1][0], 4, 4, 0, SCALE1, 0,        \
        SCALE1);                                                           \
    acc[ACCI + 1][1] = __builtin_amdgcn_mfma_scale_f32_32x32x64_f8f6f4(    \
        lo8(a[1]), lo8(b[1]), acc[ACCI + 1][1], 4, 4, 0, SCALE1, 0,        \
        SCALE1);                                                           \
    __builtin_amdgcn_s_setprio(0);                                         \
  } while (0)

template <int VM, bool ISSUE>
__device__ __forceinline__ void tile_step(
    int t, const uint8_t* __restrict__ Asrc, const uint8_t* __restrict__ Bsrc,
    long off0, long off1, int dstOff, uint8_t* lds, int aRd, int bRd,
    f32x16 (&acc)[4][2]) {
  const uint8_t* buf = lds + (t & 3) * 32768;
  uint8_t* nbuf = lds + ((t + 3) & 3) * 32768;
  long kn = (long)(t + 3) * 64;
  i32x4 a[2], b[2];
  // ---- phase 1: h0, mi 0-1 ----
  a[0] = *reinterpret_cast<const i32x4*>(buf + aRd);
  a[1] = *reinterpret_cast<const i32x4*>(buf + aRd + 2048);
  b[0] = *reinterpret_cast<const i32x4*>(buf + bRd);
  b[1] = *reinterpret_cast<const i32x4*>(buf + bRd + 2048);
  if (ISSUE) gload_lds16(Asrc + off0 + kn, nbuf + dstOff);
  barrier_raw();
  MFMA4(0);
  barrier_raw();
  // ---- phase 2: h0, mi 2-3 (b reused) ----
  a[0] = *reinterpret_cast<const i32x4*>(buf + aRd + 2 * 2048);
  a[1] = *reinterpret_cast<const i32x4*>(buf + aRd + 3 * 2048);
  if (ISSUE) gload_lds16(Asrc + off1 + kn, nbuf + 8192 + dstOff);
  barrier_raw();
  MFMA4(2);
  barrier_raw();
  // ---- phase 3: h1, mi 0-1, new b ----
  a[0] = *reinterpret_cast<const i32x4*>(buf + aRd + 1024);
  a[1] = *reinterpret_cast<const i32x4*>(buf + aRd + 2048 + 1024);
  b[0] = *reinterpret_cast<const i32x4*>(buf + bRd + 1024);
  b[1] = *reinterpret_cast<const i32x4*>(buf + bRd + 2048 + 1024);
  if (ISSUE) gload_lds16(Bsrc + off0 + kn, nbuf + 16384 + dstOff);
  barrier_raw();
  MFMA4(0);
  barrier_raw();
  // ---- phase 4: h1, mi 2-3 + once-per-tile vm gate ----
  a[0] = *reinterpret_cast<const i32x4*>(buf + aRd + 2 * 2048 + 1024);
  a[1] = *reinterpret_cast<const i32x4*>(buf + aRd + 3 * 2048 + 1024);
  if (ISSUE) gload_lds16(Bsrc + off1 + kn, nbuf + 24576 + dstOff);
  if (VM == 8) asm volatile("s_waitcnt vmcnt(8)" ::: "memory");
  else if (VM == 4) asm volatile("s_waitcnt vmcnt(4)" ::: "memory");
  else if (VM == 0) asm volatile("s_waitcnt vmcnt(0)" ::: "memory");
  barrier_raw();  // gate barrier: all waves' t+1 staging visible
  MFMA4(2);
  barrier_raw();
}

__global__ __launch_bounds__(512, 2) void gemm_fp4_kernel(
    const uint8_t* __restrict__ A, const uint8_t* __restrict__ B,
    float* __restrict__ C) {
  __shared__ __align__(16) uint8_t lds[4 * 32768];  // 128 KiB

  // R12 L2-locality XCD mapping (FETCH -33%): bijective over 32bm x 16bn
  int bid = blockIdx.x;
  int xcd = bid & 7;
  int i = bid >> 3;
  int bn = (i & 7) + ((xcd & 1) << 3);
  int bm = (i >> 3) + ((xcd >> 1) << 3);

  int tid = threadIdx.x;
  int wid = tid >> 6;
  int lane = tid & 63;
  int wr = wid >> 2;  // 0..1 (M)
  int wc = wid & 3;   // 0..3 (N)

  const uint8_t* Asrc = A + (long)bm * 256 * KB2;
  const uint8_t* Bsrc = B + (long)bn * 256 * KB2;

  // staging decomp for slot s = j*512 + tid: mb=s>>7, c=(s>>5)&3, row=s&31
  long off0 = (long)((tid >> 7) * 32 + (tid & 31)) * KB2 + (((tid >> 5) & 3) << 4);
  long off1 = off0 + 128L * KB2;
  int dstOff = wid * 1024;  // wave-uniform; HW adds lane*16

  // frag read bases (linear lane*16): A mb = wr*4 + mi, B nb = wc*2 + ni
  int aRd = (wr * 4) * 2048 + lane * 16;
  int bRd = 16384 + (wc * 2) * 2048 + lane * 16;

  f32x16 acc[4][2] = {};

  // prologue: stage tiles 0,1,2 (12 loads in flight)
#pragma unroll
  for (int t = 0; t < 3; ++t) {
    uint8_t* buf = lds + t * 32768;
    long k0 = (long)t * 64;
    gload_lds16(Asrc + off0 + k0, buf + dstOff);
    gload_lds16(Asrc + off1 + k0, buf + 8192 + dstOff);
    gload_lds16(Bsrc + off0 + k0, buf + 16384 + dstOff);
    gload_lds16(Bsrc + off1 + k0, buf + 24576 + dstOff);
  }
  asm volatile("s_waitcnt vmcnt(8)" ::: "memory");  // tile 0 landed
  barrier_raw();

#pragma unroll 1
  for (int t = 0; t < 29; ++t)
    tile_step<8, true>(t, Asrc, Bsrc, off0, off1, dstOff, lds, aRd, bRd, acc);
  tile_step<4, false>(29, Asrc, Bsrc, off0, off1, dstOff, lds, aRd, bRd, acc);
  tile_step<0, false>(30, Asrc, Bsrc, off0, off1, dstOff, lds, aRd, bRd, acc);
  tile_step<-1, false>(31, Asrc, Bsrc, off0, off1, dstOff, lds, aRd, bRd, acc);

  // C/D 32x32 layout: col = lane&31, row = (reg&3) + 8*(reg>>2) + 4*(lane>>5)
  long row0 = (long)bm * 256 + wr * 128 + ((lane >> 5) << 2);
  long col0 = (long)bn * 256 + wc * 64 + (lane & 31);
#pragma unroll
  for (int mi = 0; mi < 4; ++mi)
#pragma unroll
    for (int ni = 0; ni < 2; ++ni)
#pragma unroll
      for (int r = 0; r < 16; ++r) {
        long row = row0 + mi * 32 + (r & 3) + ((r >> 2) << 3);
        C[row * N_DIM + col0 + ni * 32] = acc[mi][ni][r];
      }
}

extern "C" void kernel_launch(void* const* d_in, const int* in_sizes, int n_in,
                              void* d_out, int out_size, void* d_ws, size_t ws_size,
                              hipStream_t stream) {
  const float* x = (const float*)d_in[0];
  const float* w = (const float*)d_in[1];
  float* out = (float*)d_out;

  uint8_t* x4 = (uint8_t*)d_ws;                     // 16 MB: fp4 sign(x) [M][K/2]
  uint8_t* w4t = x4 + (size_t)M_DIM * KB2;          // 8 MB: fp4 sign(w)^T [N][K/2]

  pack_x4_kernel<<<2048, 256, 0, stream>>>(x, (unsigned*)x4,
                                           (long)M_DIM * K_DIM / 8);
  pack_wt4_kernel<<<dim3(N_DIM / 64, K_DIM / 64), 256, 0, stream>>>(
      w, (unsigned*)w4t);
  gemm_fp4_kernel<<<512, 512, 0, stream>>>(x4, w4t, out);
}

// Round 14
// 132.090 us; speedup vs baseline: 1.2150x; 1.0672x over previous
//
#include <hip/hip_runtime.h>
#include <stdint.h>

#define M_DIM 8192
#define K_DIM 4096
#define N_DIM 4096

using i32x4 = __attribute__((ext_vector_type(4))) int;
using i32x8 = __attribute__((ext_vector_type(8))) int;
using f32x16 = __attribute__((ext_vector_type(16))) float;

typedef const __attribute__((address_space(1))) void g_void;
typedef __attribute__((address_space(3))) void lds_void;

__device__ __forceinline__ void gload_lds16(const void* g, void* l) {
  __builtin_amdgcn_global_load_lds((g_void*)g, (lds_void*)l, 16, 0, 0);
}

__device__ __forceinline__ void barrier_raw() {
  asm volatile("" ::: "memory");
  __builtin_amdgcn_s_barrier();
  asm volatile("" ::: "memory");
}

// fp4 e2m1: +1 = 0x2 (1.0), -1 = 0xA, 0 = 0x0
__device__ __forceinline__ unsigned code4(float v) {
  return v > 0.f ? 0x2u : (v < 0.f ? 0xAu : 0x0u);
}

// ---- pack x: fp32 [M][K] -> GEMM-ready fp4: [g=M/32][t=K/128][kc=4][row=32]x16B
// Block = (g, quarter-of-K). Coalesced float4 reads -> LDS u16 codes ->
// coalesced 16B-unit writes in output-linear order.
__global__ void pack_x4_kernel(const float* __restrict__ in,
                               uint8_t* __restrict__ out) {
  __shared__ __align__(16) uint16_t cds[32 * 264];  // [row][c4], pad stride 264
  int g = blockIdx.x;   // 0..255
  int tq = blockIdx.y;  // 0..3 (1024-elem quarter of K)
  int tid = threadIdx.x;
#pragma unroll
  for (int i = 0; i < 32; ++i) {
    int flat = tid + 256 * i;  // 0..8191 float4s
    int row = flat >> 8;
    int c4 = flat & 255;
    const float4 v = *reinterpret_cast<const float4*>(
        in + (long)(g * 32 + row) * K_DIM + tq * 1024 + c4 * 4);
    unsigned u = code4(v.x) | (code4(v.y) << 4) | (code4(v.z) << 8) |
                 (code4(v.w) << 12);
    cds[row * 264 + c4] = (uint16_t)u;
  }
  __syncthreads();
#pragma unroll
  for (int j = 0; j < 4; ++j) {
    int u = tid + 256 * j;  // 0..1023 output 16B units
    int tl = u >> 7;        // ktile-local 0..7
    int kc = (u >> 5) & 3;
    int row = u & 31;
    i32x4 val = *reinterpret_cast<const i32x4*>(
        &cds[row * 264 + tl * 32 + kc * 8]);  // 8 u16 = 16B, aligned (264*2%16==0)
    int t = tq * 8 + tl;
    long o = ((((long)g * 32 + t) * 4 + kc) * 32 + row) * 16;
    *reinterpret_cast<i32x4*>(out + o) = val;
  }
}

// ---- pack w: fp32 [K][N] -> GEMM-ready fp4 W^T: [g=N/32][t][kc][row32]x16B
__global__ void pack_wt4_kernel(const float* __restrict__ w,
                                uint8_t* __restrict__ out) {
  __shared__ __align__(16) uint8_t tile[64 * 144];  // codes [n64][k128], stride 144
  int n0 = blockIdx.x * 64;
  int k0 = blockIdx.y * 128;
  int tid = threadIdx.x;
#pragma unroll
  for (int i = 0; i < 32; ++i) {
    int flat = tid + 256 * i;  // 128k x 64n
    int r = flat >> 6;         // k-local
    int c = flat & 63;         // n-local (coalesced)
    tile[c * 144 + r] = (uint8_t)code4(w[(long)(k0 + r) * N_DIM + n0 + c]);
  }
  __syncthreads();
  // 256 output units of 16B (32 codes nibble-packed)
  int rg = tid >> 7, kc = (tid >> 5) & 3, row = tid & 31;
  const unsigned* sp =
      reinterpret_cast<const unsigned*>(&tile[(rg * 32 + row) * 144 + kc * 32]);
  i32x4 val;
#pragma unroll
  for (int d = 0; d < 4; ++d) {
    unsigned s0 = sp[2 * d], s1 = sp[2 * d + 1];
    unsigned t0 = s0 & 0x0F0F0F0Fu, t1 = s1 & 0x0F0F0F0Fu;
    unsigned p = (t0 | (t0 >> 4)) & 0x00FF00FFu;  // ab @[7:0], cd @[23:16]
    unsigned q = (t1 | (t1 >> 4)) & 0x00FF00FFu;
    val[d] = (int)((p & 0xFFu) | ((p >> 8) & 0xFF00u) | ((q & 0xFFu) << 16) |
                   ((q >> 16) << 24));
  }
  int g = (n0 >> 5) + rg;
  int t = k0 >> 7;
  long o = ((((long)g * 32 + t) * 4 + kc) * 32 + row) * 16;
  *reinterpret_cast<i32x4*>(out + o) = val;
}

// ---- MX-fp4 GEMM: R9 schedule + R12 mapping + COALESCED staging.
// Workspace layout [g][t][kc][row]x16B makes each tile-stage = 2x 1024
// contiguous bytes per wave per operand (16 fully-used lines/instr, vs
// R9-R13's 32-line gather = the ~2100 cyc/tile TA stall all schedule
// variants shared). LDS image and frag reads are BIT-IDENTICAL to R9.
__device__ __forceinline__ i32x8 lo8(i32x4 r) {
  return __builtin_shufflevector(r, r, 0, 1, 2, 3, -1, -1, -1, -1);
}

#define SCALE1 0x7f7f7f7f  // E8M0 1.0 in every byte

template <int VM, bool ISSUE>
__device__ __forceinline__ void tile_step(
    int t, const uint8_t* __restrict__ gA, const uint8_t* __restrict__ gB,
    int dstA, int dstB, uint8_t* lds, int aRd, int bRd, f32x16 (&acc)[4][2]) {
  const uint8_t* buf = lds + (t & 3) * 32768;
  // stage tile t+3 into slot (t+3)&3 (R9-proven WAR ledger), contiguous
  if (ISSUE) {
    long kn = (long)(t + 3) * 2048;
    uint8_t* nbuf = lds + ((t + 3) & 3) * 32768;
    gload_lds16(gA + kn, nbuf + dstA);
    gload_lds16(gA + kn + 1024, nbuf + dstA + 1024);
    gload_lds16(gB + kn, nbuf + dstB);
    gload_lds16(gB + kn + 1024, nbuf + dstB + 1024);
  }
  // all 12 frag reads: h0 first (lgkm(6) retires exactly those)
  i32x4 a0[4], b0[2], a1[4], b1[2];
#pragma unroll
  for (int mi = 0; mi < 4; ++mi)
    a0[mi] = *reinterpret_cast<const i32x4*>(buf + aRd + mi * 2048);
#pragma unroll
  for (int ni = 0; ni < 2; ++ni)
    b0[ni] = *reinterpret_cast<const i32x4*>(buf + bRd + ni * 2048);
#pragma unroll
  for (int mi = 0; mi < 4; ++mi)
    a1[mi] = *reinterpret_cast<const i32x4*>(buf + aRd + mi * 2048 + 1024);
#pragma unroll
  for (int ni = 0; ni < 2; ++ni)
    b1[ni] = *reinterpret_cast<const i32x4*>(buf + bRd + ni * 2048 + 1024);
  asm volatile("s_waitcnt lgkmcnt(6)" ::: "memory");  // h0 ready, h1 in flight
  __builtin_amdgcn_sched_barrier(0);
  __builtin_amdgcn_s_setprio(1);
#pragma unroll
  for (int mi = 0; mi < 4; ++mi)
#pragma unroll
    for (int ni = 0; ni < 2; ++ni)
      acc[mi][ni] = __builtin_amdgcn_mfma_scale_f32_32x32x64_f8f6f4(
          lo8(a0[mi]), lo8(b0[ni]), acc[mi][ni], 4, 4, 0, SCALE1, 0, SCALE1);
  __builtin_amdgcn_s_setprio(0);
  asm volatile("s_waitcnt lgkmcnt(0)" ::: "memory");  // h1 ready
  __builtin_amdgcn_sched_barrier(0);
  __builtin_amdgcn_s_setprio(1);
#pragma unroll
  for (int mi = 0; mi < 4; ++mi)
#pragma unroll
    for (int ni = 0; ni < 2; ++ni)
      acc[mi][ni] = __builtin_amdgcn_mfma_scale_f32_32x32x64_f8f6f4(
          lo8(a1[mi]), lo8(b1[ni]), acc[mi][ni], 4, 4, 0, SCALE1, 0, SCALE1);
  __builtin_amdgcn_s_setprio(0);
  // gate: tile t+1 landed for all waves (vmcnt(8) = tiles t+2,t+3 in flight)
  if (VM >= 0) {
    if (VM == 8) asm volatile("s_waitcnt vmcnt(8)" ::: "memory");
    else if (VM == 4) asm volatile("s_waitcnt vmcnt(4)" ::: "memory");
    else asm volatile("s_waitcnt vmcnt(0)" ::: "memory");
    barrier_raw();
  }
}

__global__ __launch_bounds__(512, 2) void gemm_fp4_kernel(
    const uint8_t* __restrict__ A, const uint8_t* __restrict__ B,
    float* __restrict__ C) {
  __shared__ __align__(16) uint8_t lds[4 * 32768];  // 128 KiB

  // R12 L2-locality XCD mapping (bijective over 32bm x 16bn)
  int bid = blockIdx.x;
  int xcd = bid & 7;
  int i = bid >> 3;
  int bn = (i & 7) + ((xcd & 1) << 3);
  int bm = (i >> 3) + ((xcd >> 1) << 3);

  int tid = threadIdx.x;
  int wid = tid >> 6;
  int lane = tid & 63;
  int wr = wid >> 2;  // 0..1 (M)
  int wc = wid & 3;   // 0..3 (N)

  // per-wave staging bases: wave wid owns row-group (panel*8 + wid);
  // per-lane +lane*16 (global src is per-lane; LDS dest wave-uniform)
  const uint8_t* gA = A + (long)(bm * 8 + wid) * 32 * 2048 + lane * 16;
  const uint8_t* gB = B + (long)(bn * 8 + wid) * 32 * 2048 + lane * 16;
  int dstA = wid * 2048;          // A region [0, 16K)
  int dstB = 16384 + wid * 2048;  // B region [16K, 32K)

  // frag read bases (unchanged from R9): A mb = wr*4 + mi, B nb = wc*2 + ni
  int aRd = (wr * 4) * 2048 + lane * 16;
  int bRd = 16384 + (wc * 2) * 2048 + lane * 16;

  f32x16 acc[4][2] = {};

  // prologue: stage tiles 0,1,2 (12 loads in flight)
#pragma unroll
  for (int t = 0; t < 3; ++t) {
    uint8_t* buf = lds + t * 32768;
    long k0 = (long)t * 2048;
    gload_lds16(gA + k0, buf + dstA);
    gload_lds16(gA + k0 + 1024, buf + dstA + 1024);
    gload_lds16(gB + k0, buf + dstB);
    gload_lds16(gB + k0 + 1024, buf + dstB + 1024);
  }
  asm volatile("s_waitcnt vmcnt(8)" ::: "memory");  // tile 0 landed
  barrier_raw();

#pragma unroll 1
  for (int t = 0; t < 29; ++t)
    tile_step<8, true>(t, gA, gB, dstA, dstB, lds, aRd, bRd, acc);
  tile_step<4, false>(29, gA, gB, dstA, dstB, lds, aRd, bRd, acc);
  tile_step<0, false>(30, gA, gB, dstA, dstB, lds, aRd, bRd, acc);
  tile_step<-1, false>(31, gA, gB, dstA, dstB, lds, aRd, bRd, acc);

  // C/D 32x32 layout: col = lane&31, row = (reg&3) + 8*(reg>>2) + 4*(lane>>5)
  long row0 = (long)bm * 256 + wr * 128 + ((lane >> 5) << 2);
  long col0 = (long)bn * 256 + wc * 64 + (lane & 31);
#pragma unroll
  for (int mi = 0; mi < 4; ++mi)
#pragma unroll
    for (int ni = 0; ni < 2; ++ni)
#pragma unroll
      for (int r = 0; r < 16; ++r) {
        long row = row0 + mi * 32 + (r & 3) + ((r >> 2) << 3);
        C[row * N_DIM + col0 + ni * 32] = acc[mi][ni][r];
      }
}

extern "C" void kernel_launch(void* const* d_in, const int* in_sizes, int n_in,
                              void* d_out, int out_size, void* d_ws, size_t ws_size,
                              hipStream_t stream) {
  const float* x = (const float*)d_in[0];
  const float* w = (const float*)d_in[1];
  float* out = (float*)d_out;

  uint8_t* x4 = (uint8_t*)d_ws;                        // 16 MB GEMM-ready A
  uint8_t* w4t = x4 + (size_t)M_DIM * (K_DIM / 2);     // 8 MB GEMM-ready W^T

  pack_x4_kernel<<<dim3(M_DIM / 32, 4), 256, 0, stream>>>(x, x4);
  pack_wt4_kernel<<<dim3(N_DIM / 64, K_DIM / 128), 256, 0, stream>>>(w, w4t);
  gemm_fp4_kernel<<<512, 512, 0, stream>>>(x4, w4t, out);
}

// Round 15
// 131.113 us; speedup vs baseline: 1.2240x; 1.0075x over previous
//
#include <hip/hip_runtime.h>
#include <stdint.h>

#define M_DIM 8192
#define K_DIM 4096
#define N_DIM 4096

using i32x4 = __attribute__((ext_vector_type(4))) int;
using i32x8 = __attribute__((ext_vector_type(8))) int;
using f32x16 = __attribute__((ext_vector_type(16))) float;

typedef const __attribute__((address_space(1))) void g_void;
typedef __attribute__((address_space(3))) void lds_void;

__device__ __forceinline__ void gload_lds16(const void* g, void* l) {
  __builtin_amdgcn_global_load_lds((g_void*)g, (lds_void*)l, 16, 0, 0);
}

__device__ __forceinline__ void barrier_raw() {
  asm volatile("" ::: "memory");
  __builtin_amdgcn_s_barrier();
  asm volatile("" ::: "memory");
}

// fp4 e2m1: +1 = 0x2 (1.0), -1 = 0xA, 0 = 0x0
__device__ __forceinline__ unsigned code4(float v) {
  return v > 0.f ? 0x2u : (v < 0.f ? 0xAu : 0x0u);
}

// ---- pack x: fp32 [M][K] -> GEMM-ready fp4 [g=M/32][t=K/128][kc=4][row=32]x16B
__global__ void pack_x4_kernel(const float* __restrict__ in,
                               uint8_t* __restrict__ out) {
  __shared__ __align__(16) uint16_t cds[32 * 264];
  int g = blockIdx.x;
  int tq = blockIdx.y;
  int tid = threadIdx.x;
#pragma unroll
  for (int i = 0; i < 32; ++i) {
    int flat = tid + 256 * i;
    int row = flat >> 8;
    int c4 = flat & 255;
    const float4 v = *reinterpret_cast<const float4*>(
        in + (long)(g * 32 + row) * K_DIM + tq * 1024 + c4 * 4);
    unsigned u = code4(v.x) | (code4(v.y) << 4) | (code4(v.z) << 8) |
                 (code4(v.w) << 12);
    cds[row * 264 + c4] = (uint16_t)u;
  }
  __syncthreads();
#pragma unroll
  for (int j = 0; j < 4; ++j) {
    int u = tid + 256 * j;
    int tl = u >> 7;
    int kc = (u >> 5) & 3;
    int row = u & 31;
    i32x4 val = *reinterpret_cast<const i32x4*>(&cds[row * 264 + tl * 32 + kc * 8]);
    int t = tq * 8 + tl;
    long o = ((((long)g * 32 + t) * 4 + kc) * 32 + row) * 16;
    *reinterpret_cast<i32x4*>(out + o) = val;
  }
}

// ---- pack w: fp32 [K][N] -> GEMM-ready fp4 W^T [g=N/32][t][kc][row32]x16B
__global__ void pack_wt4_kernel(const float* __restrict__ w,
                                uint8_t* __restrict__ out) {
  __shared__ __align__(16) uint8_t tile[64 * 144];
  int n0 = blockIdx.x * 64;
  int k0 = blockIdx.y * 128;
  int tid = threadIdx.x;
#pragma unroll
  for (int i = 0; i < 32; ++i) {
    int flat = tid + 256 * i;
    int r = flat >> 6;
    int c = flat & 63;
    tile[c * 144 + r] = (uint8_t)code4(w[(long)(k0 + r) * N_DIM + n0 + c]);
  }
  __syncthreads();
  int rg = tid >> 7, kc = (tid >> 5) & 3, row = tid & 31;
  const unsigned* sp =
      reinterpret_cast<const unsigned*>(&tile[(rg * 32 + row) * 144 + kc * 32]);
  i32x4 val;
#pragma unroll
  for (int d = 0; d < 4; ++d) {
    unsigned s0 = sp[2 * d], s1 = sp[2 * d + 1];
    unsigned t0 = s0 & 0x0F0F0F0Fu, t1 = s1 & 0x0F0F0F0Fu;
    unsigned p = (t0 | (t0 >> 4)) & 0x00FF00FFu;
    unsigned q = (t1 | (t1 >> 4)) & 0x00FF00FFu;
    val[d] = (int)((p & 0xFFu) | ((p >> 8) & 0xFF00u) | ((q & 0xFFu) << 16) |
                   ((q >> 16) << 24));
  }
  int g = (n0 >> 5) + rg;
  int t = k0 >> 7;
  long o = ((((long)g * 32 + t) * 4 + kc) * 32 + row) * 16;
  *reinterpret_cast<i32x4*>(out + o) = val;
}

// ---- MX-fp4 GEMM: R14 coalesced staging + R10 cross-barrier read pipeline.
// R10's schedule was null UNDER the TA-scatter stall (wrong regime); with
// staging coalesced the tile-start read-drain is now on the critical path,
// which this schedule removes. Per tile:
//  a) lgkm(6) -> MFMA h0          [t's h1 reads drain underneath]
//  b) vmcnt(4) + barrier          [t+1's 4 staging loads landed, all waves]
//  c) stage t+3 + issue 12 reads of t+1 (h0 first) into ping-pong set
//  d) lgkm(12) -> MFMA h1         [t+1's reads drain underneath]
// WAR: slot (t+3)&3=(t-1)&3; all t-1 reads retired at t-1's step-d
// lgkm(12), one barrier before this write.
__device__ __forceinline__ i32x8 lo8(i32x4 r) {
  return __builtin_shufflevector(r, r, 0, 1, 2, 3, -1, -1, -1, -1);
}

#define SCALE1 0x7f7f7f7f  // E8M0 1.0 in every byte

template <int VM, bool ISSUE, bool READ>
__device__ __forceinline__ void tile_step(
    int t, const uint8_t* __restrict__ gA, const uint8_t* __restrict__ gB,
    int dstA, int dstB, uint8_t* lds, int aRd, int bRd, i32x4 (&aC)[8],
    i32x4 (&bC)[4], i32x4 (&aN)[8], i32x4 (&bN)[4], f32x16 (&acc)[4][2]) {
  // ---- a: MFMA h0(t) ----
  asm volatile("s_waitcnt lgkmcnt(6)" ::: "memory");  // t.h0 frags ready
  __builtin_amdgcn_sched_barrier(0);
  __builtin_amdgcn_s_setprio(1);
#pragma unroll
  for (int mi = 0; mi < 4; ++mi)
#pragma unroll
    for (int ni = 0; ni < 2; ++ni)
      acc[mi][ni] = __builtin_amdgcn_mfma_scale_f32_32x32x64_f8f6f4(
          lo8(aC[mi]), lo8(bC[ni]), acc[mi][ni], 4, 4, 0, SCALE1, 0, SCALE1);
  __builtin_amdgcn_s_setprio(0);
  // ---- b: vm-gate + single barrier per tile ----
  if (VM >= 0) {
    if (VM == 4) asm volatile("s_waitcnt vmcnt(4)" ::: "memory");
    else asm volatile("s_waitcnt vmcnt(0)" ::: "memory");
    barrier_raw();
  }
  // ---- c: stage t+3 (contiguous 1KB x2 per operand) + read t+1 frags ----
  if (ISSUE) {
    long kn = (long)(t + 3) * 2048;
    uint8_t* nbuf = lds + ((t + 3) & 3) * 32768;
    gload_lds16(gA + kn, nbuf + dstA);
    gload_lds16(gA + kn + 1024, nbuf + dstA + 1024);
    gload_lds16(gB + kn, nbuf + dstB);
    gload_lds16(gB + kn + 1024, nbuf + dstB + 1024);
  }
  if (READ) {
    const uint8_t* nb = lds + ((t + 1) & 3) * 32768;
#pragma unroll
    for (int mi = 0; mi < 4; ++mi)
      aN[mi] = *reinterpret_cast<const i32x4*>(nb + aRd + mi * 2048);
#pragma unroll
    for (int ni = 0; ni < 2; ++ni)
      bN[ni] = *reinterpret_cast<const i32x4*>(nb + bRd + ni * 2048);
#pragma unroll
    for (int mi = 0; mi < 4; ++mi)
      aN[4 + mi] = *reinterpret_cast<const i32x4*>(nb + aRd + mi * 2048 + 1024);
#pragma unroll
    for (int ni = 0; ni < 2; ++ni)
      bN[2 + ni] = *reinterpret_cast<const i32x4*>(nb + bRd + ni * 2048 + 1024);
  }
  // ---- d: MFMA h1(t) ----
  if (READ)
    asm volatile("s_waitcnt lgkmcnt(12)" ::: "memory");  // t.h1 ready, t+1 in flight
  else
    asm volatile("s_waitcnt lgkmcnt(0)" ::: "memory");
  __builtin_amdgcn_sched_barrier(0);
  __builtin_amdgcn_s_setprio(1);
#pragma unroll
  for (int mi = 0; mi < 4; ++mi)
#pragma unroll
    for (int ni = 0; ni < 2; ++ni)
      acc[mi][ni] = __builtin_amdgcn_mfma_scale_f32_32x32x64_f8f6f4(
          lo8(aC[4 + mi]), lo8(bC[2 + ni]), acc[mi][ni], 4, 4, 0, SCALE1, 0,
          SCALE1);
  __builtin_amdgcn_s_setprio(0);
}

__global__ __launch_bounds__(512, 2) void gemm_fp4_kernel(
    const uint8_t* __restrict__ A, const uint8_t* __restrict__ B,
    float* __restrict__ C) {
  __shared__ __align__(16) uint8_t lds[4 * 32768];  // 128 KiB

  // R12 L2-locality XCD mapping (bijective over 32bm x 16bn)
  int bid = blockIdx.x;
  int xcd = bid & 7;
  int i = bid >> 3;
  int bn = (i & 7) + ((xcd & 1) << 3);
  int bm = (i >> 3) + ((xcd >> 1) << 3);

  int tid = threadIdx.x;
  int wid = tid >> 6;
  int lane = tid & 63;
  int wr = wid >> 2;  // 0..1 (M)
  int wc = wid & 3;   // 0..3 (N)

  // per-wave staging bases (contiguous GEMM-ready layout)
  const uint8_t* gA = A + (long)(bm * 8 + wid) * 32 * 2048 + lane * 16;
  const uint8_t* gB = B + (long)(bn * 8 + wid) * 32 * 2048 + lane * 16;
  int dstA = wid * 2048;
  int dstB = 16384 + wid * 2048;

  // frag read bases: A mb = wr*4 + mi, B nb = wc*2 + ni
  int aRd = (wr * 4) * 2048 + lane * 16;
  int bRd = 16384 + (wc * 2) * 2048 + lane * 16;

  i32x4 aA[8], bA[4], aB[8], bB[4];
  f32x16 acc[4][2] = {};

  // prologue: stage tiles 0,1,2
#pragma unroll
  for (int t = 0; t < 3; ++t) {
    uint8_t* buf = lds + t * 32768;
    long k0 = (long)t * 2048;
    gload_lds16(gA + k0, buf + dstA);
    gload_lds16(gA + k0 + 1024, buf + dstA + 1024);
    gload_lds16(gB + k0, buf + dstB);
    gload_lds16(gB + k0 + 1024, buf + dstB + 1024);
  }
  asm volatile("s_waitcnt vmcnt(8)" ::: "memory");  // tile 0 landed
  barrier_raw();
  // issue tile-0 frag reads (h0 first) into set A
#pragma unroll
  for (int mi = 0; mi < 4; ++mi)
    aA[mi] = *reinterpret_cast<const i32x4*>(lds + aRd + mi * 2048);
#pragma unroll
  for (int ni = 0; ni < 2; ++ni)
    bA[ni] = *reinterpret_cast<const i32x4*>(lds + bRd + ni * 2048);
#pragma unroll
  for (int mi = 0; mi < 4; ++mi)
    aA[4 + mi] = *reinterpret_cast<const i32x4*>(lds + aRd + mi * 2048 + 1024);
#pragma unroll
  for (int ni = 0; ni < 2; ++ni)
    bA[2 + ni] = *reinterpret_cast<const i32x4*>(lds + bRd + ni * 2048 + 1024);

#pragma unroll 1
  for (int t = 0; t < 28; t += 2) {
    tile_step<4, true, true>(t, gA, gB, dstA, dstB, lds, aRd, bRd, aA, bA, aB,
                             bB, acc);
    tile_step<4, true, true>(t + 1, gA, gB, dstA, dstB, lds, aRd, bRd, aB, bB,
                             aA, bA, acc);
  }
  tile_step<4, true, true>(28, gA, gB, dstA, dstB, lds, aRd, bRd, aA, bA, aB,
                           bB, acc);  // stages tile 31
  tile_step<4, false, true>(29, gA, gB, dstA, dstB, lds, aRd, bRd, aB, bB, aA,
                            bA, acc);
  tile_step<0, false, true>(30, gA, gB, dstA, dstB, lds, aRd, bRd, aA, bA, aB,
                            bB, acc);
  tile_step<-1, false, false>(31, gA, gB, dstA, dstB, lds, aRd, bRd, aB, bB,
                              aA, bA, acc);

  // C/D 32x32 layout: col = lane&31, row = (reg&3) + 8*(reg>>2) + 4*(lane>>5)
  long row0 = (long)bm * 256 + wr * 128 + ((lane >> 5) << 2);
  long col0 = (long)bn * 256 + wc * 64 + (lane & 31);
#pragma unroll
  for (int mi = 0; mi < 4; ++mi)
#pragma unroll
    for (int ni = 0; ni < 2; ++ni)
#pragma unroll
      for (int r = 0; r < 16; ++r) {
        long row = row0 + mi * 32 + (r & 3) + ((r >> 2) << 3);
        C[row * N_DIM + col0 + ni * 32] = acc[mi][ni][r];
      }
}

extern "C" void kernel_launch(void* const* d_in, const int* in_sizes, int n_in,
                              void* d_out, int out_size, void* d_ws, size_t ws_size,
                              hipStream_t stream) {
  const float* x = (const float*)d_in[0];
  const float* w = (const float*)d_in[1];
  float* out = (float*)d_out;

  uint8_t* x4 = (uint8_t*)d_ws;                     // 16 MB GEMM-ready A
  uint8_t* w4t = x4 + (size_t)M_DIM * (K_DIM / 2);  // 8 MB GEMM-ready W^T

  pack_x4_kernel<<<dim3(M_DIM / 32, 4), 256, 0, stream>>>(x, x4);
  pack_wt4_kernel<<<dim3(N_DIM / 64, K_DIM / 128), 256, 0, stream>>>(w, w4t);
  gemm_fp4_kernel<<<512, 512, 0, stream>>>(x4, w4t, out);
}

// Round 16
// 124.474 us; speedup vs baseline: 1.2893x; 1.0533x over previous
//
#include <hip/hip_runtime.h>
#include <stdint.h>

#define M_DIM 8192
#define K_DIM 4096
#define N_DIM 4096

using i32x4 = __attribute__((ext_vector_type(4))) int;
using i32x8 = __attribute__((ext_vector_type(8))) int;
using f32x16 = __attribute__((ext_vector_type(16))) float;

typedef const __attribute__((address_space(1))) void g_void;
typedef __attribute__((address_space(3))) void lds_void;

__device__ __forceinline__ void gload_lds16(const void* g, void* l) {
  __builtin_amdgcn_global_load_lds((g_void*)g, (lds_void*)l, 16, 0, 0);
}

__device__ __forceinline__ void barrier_raw() {
  asm volatile("" ::: "memory");
  __builtin_amdgcn_s_barrier();
  asm volatile("" ::: "memory");
}

// fp4 e2m1: +1 = 0x2 (1.0), -1 = 0xA, 0 = 0x0
__device__ __forceinline__ unsigned code4(float v) {
  return v > 0.f ? 0x2u : (v < 0.f ? 0xAu : 0x0u);
}

// ---- pack x: fp32 [M][K] -> GEMM-ready fp4 [g=M/32][t=K/128][kc=4][row=32]x16B
__global__ void pack_x4_kernel(const float* __restrict__ in,
                               uint8_t* __restrict__ out) {
  __shared__ __align__(16) uint16_t cds[32 * 264];
  int g = blockIdx.x;
  int tq = blockIdx.y;
  int tid = threadIdx.x;
#pragma unroll
  for (int i = 0; i < 32; ++i) {
    int flat = tid + 256 * i;
    int row = flat >> 8;
    int c4 = flat & 255;
    const float4 v = *reinterpret_cast<const float4*>(
        in + (long)(g * 32 + row) * K_DIM + tq * 1024 + c4 * 4);
    unsigned u = code4(v.x) | (code4(v.y) << 4) | (code4(v.z) << 8) |
                 (code4(v.w) << 12);
    cds[row * 264 + c4] = (uint16_t)u;
  }
  __syncthreads();
#pragma unroll
  for (int j = 0; j < 4; ++j) {
    int u = tid + 256 * j;
    int tl = u >> 7;
    int kc = (u >> 5) & 3;
    int row = u & 31;
    i32x4 val = *reinterpret_cast<const i32x4*>(&cds[row * 264 + tl * 32 + kc * 8]);
    int t = tq * 8 + tl;
    long o = ((((long)g * 32 + t) * 4 + kc) * 32 + row) * 16;
    *reinterpret_cast<i32x4*>(out + o) = val;
  }
}

// ---- pack w: fp32 [K][N] -> GEMM-ready fp4 W^T [g=N/32][t][kc][row32]x16B
__global__ void pack_wt4_kernel(const float* __restrict__ w,
                                uint8_t* __restrict__ out) {
  __shared__ __align__(16) uint8_t tile[64 * 144];
  int n0 = blockIdx.x * 64;
  int k0 = blockIdx.y * 128;
  int tid = threadIdx.x;
#pragma unroll
  for (int i = 0; i < 32; ++i) {
    int flat = tid + 256 * i;
    int r = flat >> 6;
    int c = flat & 63;
    tile[c * 144 + r] = (uint8_t)code4(w[(long)(k0 + r) * N_DIM + n0 + c]);
  }
  __syncthreads();
  int rg = tid >> 7, kc = (tid >> 5) & 3, row = tid & 31;
  const unsigned* sp =
      reinterpret_cast<const unsigned*>(&tile[(rg * 32 + row) * 144 + kc * 32]);
  i32x4 val;
#pragma unroll
  for (int d = 0; d < 4; ++d) {
    unsigned s0 = sp[2 * d], s1 = sp[2 * d + 1];
    unsigned t0 = s0 & 0x0F0F0F0Fu, t1 = s1 & 0x0F0F0F0Fu;
    unsigned p = (t0 | (t0 >> 4)) & 0x00FF00FFu;
    unsigned q = (t1 | (t1 >> 4)) & 0x00FF00FFu;
    val[d] = (int)((p & 0xFFu) | ((p >> 8) & 0xFF00u) | ((q & 0xFFu) << 16) |
                   ((q >> 16) << 24));
  }
  int g = (n0 >> 5) + rg;
  int t = k0 >> 7;
  long o = ((((long)g * 32 + t) * 4 + kc) * 32 + row) * 16;
  *reinterpret_cast<i32x4*>(out + o) = val;
}

// ---- MX-fp4 GEMM: 128x256 tile, 4 waves, 2 ASYNC blocks/CU ----
// R15 lesson: 1-block lockstep alternates CU-wide read-bursts and
// MFMA-bursts regardless of intra-wave order. Phase diversity must come
// from a second independent block (R4 failed on regs, R11 under TA-scatter
// -> wrong regime; both causes now removed). Budget: acc 4x2 f32x16 = 128
// + frags 48 + addr ~25 = ~200 <= 256 -> 2 waves/SIMD x 2 blocks/CU.
// LDS: ring 3 x (A 8K + B 16K) = 72 KB; 2 blocks = 144 <= 160.
// Staging coalesced (GEMM-ready layout): 6 x 1KB contiguous issues/tile.
// vmcnt ledger: stage(t+2) at top (6 loads); gate vmcnt(6) = t+1 landed,
// t+2 in flight. WAR: slot (t+2)%3=(t-1)%3, reads retired at t-1's
// lgkm(0) before its end barrier.
__device__ __forceinline__ i32x8 lo8(i32x4 r) {
  return __builtin_shufflevector(r, r, 0, 1, 2, 3, -1, -1, -1, -1);
}

#define SCALE1 0x7f7f7f7f  // E8M0 1.0 in every byte

template <int VM, bool ISSUE, int CUR>
__device__ __forceinline__ void tile_step(
    int t, const uint8_t* __restrict__ gA, const uint8_t* __restrict__ gB0,
    const uint8_t* __restrict__ gB1, int dstA, int dstB, uint8_t* lds,
    int aRd, int bRd, f32x16 (&acc)[4][2]) {
  const uint8_t* buf = lds + CUR * 24576;
  constexpr int SN = (CUR + 2) % 3;
  if (ISSUE) {
    long kn = (long)(t + 2) * 2048;
    uint8_t* nbuf = lds + SN * 24576;
    gload_lds16(gA + kn, nbuf + dstA);
    gload_lds16(gA + kn + 1024, nbuf + dstA + 1024);
    gload_lds16(gB0 + kn, nbuf + dstB);
    gload_lds16(gB0 + kn + 1024, nbuf + dstB + 1024);
    gload_lds16(gB1 + kn, nbuf + dstB + 2048);
    gload_lds16(gB1 + kn + 1024, nbuf + dstB + 3072);
  }
  // 12 frag reads, h0 first (lgkm(6) retires exactly h0)
  i32x4 a0[4], b0[2], a1[4], b1[2];
#pragma unroll
  for (int mi = 0; mi < 4; ++mi)
    a0[mi] = *reinterpret_cast<const i32x4*>(buf + aRd + mi * 2048);
#pragma unroll
  for (int ni = 0; ni < 2; ++ni)
    b0[ni] = *reinterpret_cast<const i32x4*>(buf + bRd + ni * 2048);
#pragma unroll
  for (int mi = 0; mi < 4; ++mi)
    a1[mi] = *reinterpret_cast<const i32x4*>(buf + aRd + mi * 2048 + 1024);
#pragma unroll
  for (int ni = 0; ni < 2; ++ni)
    b1[ni] = *reinterpret_cast<const i32x4*>(buf + bRd + ni * 2048 + 1024);
  asm volatile("s_waitcnt lgkmcnt(6)" ::: "memory");
  __builtin_amdgcn_sched_barrier(0);
  __builtin_amdgcn_s_setprio(1);
#pragma unroll
  for (int mi = 0; mi < 4; ++mi)
#pragma unroll
    for (int ni = 0; ni < 2; ++ni)
      acc[mi][ni] = __builtin_amdgcn_mfma_scale_f32_32x32x64_f8f6f4(
          lo8(a0[mi]), lo8(b0[ni]), acc[mi][ni], 4, 4, 0, SCALE1, 0, SCALE1);
  __builtin_amdgcn_s_setprio(0);
  asm volatile("s_waitcnt lgkmcnt(0)" ::: "memory");
  __builtin_amdgcn_sched_barrier(0);
  __builtin_amdgcn_s_setprio(1);
#pragma unroll
  for (int mi = 0; mi < 4; ++mi)
#pragma unroll
    for (int ni = 0; ni < 2; ++ni)
      acc[mi][ni] = __builtin_amdgcn_mfma_scale_f32_32x32x64_f8f6f4(
          lo8(a1[mi]), lo8(b1[ni]), acc[mi][ni], 4, 4, 0, SCALE1, 0, SCALE1);
  __builtin_amdgcn_s_setprio(0);
  if (VM >= 0) {
    if (VM == 6) asm volatile("s_waitcnt vmcnt(6)" ::: "memory");
    else asm volatile("s_waitcnt vmcnt(0)" ::: "memory");
    barrier_raw();
  }
}

__global__ __launch_bounds__(256, 2) void gemm_fp4_kernel(
    const uint8_t* __restrict__ A, const uint8_t* __restrict__ B,
    float* __restrict__ C) {
  __shared__ __align__(16) uint8_t lds[3 * 24576];  // 72 KiB

  // L2-locality XCD map: bijective over 64bm x 16bn, rectangle per XCD
  int bid = blockIdx.x;
  int xcd = bid & 7;
  int i = bid >> 3;                        // 0..127
  int bn = (i & 7) + ((xcd & 1) << 3);     // 0..15
  int bm = (i >> 3) + ((xcd >> 1) << 4);   // 0..63

  int tid = threadIdx.x;
  int wid = tid >> 6;  // 0..3 = wc (N quarter); wave owns all 128 M-rows
  int lane = tid & 63;

  // staging bases (GEMM-ready layout, fully contiguous per issue)
  const uint8_t* gA = A + (long)(bm * 4 + wid) * 65536 + lane * 16;
  const uint8_t* gB0 = B + (long)(bn * 8 + 2 * wid) * 65536 + lane * 16;
  const uint8_t* gB1 = gB0 + 65536;
  int dstA = wid * 2048;           // A region [0, 8K)
  int dstB = 8192 + wid * 4096;    // B region [8K, 24K)

  // frag reads: A mb = mi (all waves same A), B nb = wid*2 + ni
  int aRd = lane * 16;
  int bRd = 8192 + (wid * 2) * 2048 + lane * 16;

  f32x16 acc[4][2] = {};

  // prologue: stage tiles 0,1 (slots 0,1; 12 issues)
#pragma unroll
  for (int t = 0; t < 2; ++t) {
    uint8_t* buf = lds + t * 24576;
    long k0 = (long)t * 2048;
    gload_lds16(gA + k0, buf + dstA);
    gload_lds16(gA + k0 + 1024, buf + dstA + 1024);
    gload_lds16(gB0 + k0, buf + dstB);
    gload_lds16(gB0 + k0 + 1024, buf + dstB + 1024);
    gload_lds16(gB1 + k0, buf + dstB + 2048);
    gload_lds16(gB1 + k0 + 1024, buf + dstB + 3072);
  }
  asm volatile("s_waitcnt vmcnt(6)" ::: "memory");  // tile 0 landed
  barrier_raw();

#pragma unroll 1
  for (int tt = 0; tt < 30; tt += 3) {
    tile_step<6, true, 0>(tt, gA, gB0, gB1, dstA, dstB, lds, aRd, bRd, acc);
    tile_step<6, true, 1>(tt + 1, gA, gB0, gB1, dstA, dstB, lds, aRd, bRd, acc);
    tile_step<6, true, 2>(tt + 2, gA, gB0, gB1, dstA, dstB, lds, aRd, bRd, acc);
  }
  tile_step<0, false, 0>(30, gA, gB0, gB1, dstA, dstB, lds, aRd, bRd, acc);
  tile_step<-1, false, 1>(31, gA, gB0, gB1, dstA, dstB, lds, aRd, bRd, acc);

  // C/D 32x32 layout: col = lane&31, row = (reg&3) + 8*(reg>>2) + 4*(lane>>5)
  long row0 = (long)bm * 128 + ((lane >> 5) << 2);
  long col0 = (long)bn * 256 + wid * 64 + (lane & 31);
#pragma unroll
  for (int mi = 0; mi < 4; ++mi)
#pragma unroll
    for (int ni = 0; ni < 2; ++ni)
#pragma unroll
      for (int r = 0; r < 16; ++r) {
        long row = row0 + mi * 32 + (r & 3) + ((r >> 2) << 3);
        C[row * N_DIM + col0 + ni * 32] = acc[mi][ni][r];
      }
}

extern "C" void kernel_launch(void* const* d_in, const int* in_sizes, int n_in,
                              void* d_out, int out_size, void* d_ws, size_t ws_size,
                              hipStream_t stream) {
  const float* x = (const float*)d_in[0];
  const float* w = (const float*)d_in[1];
  float* out = (float*)d_out;

  uint8_t* x4 = (uint8_t*)d_ws;                     // 16 MB GEMM-ready A
  uint8_t* w4t = x4 + (size_t)M_DIM * (K_DIM / 2);  // 8 MB GEMM-ready W^T

  pack_x4_kernel<<<dim3(M_DIM / 32, 4), 256, 0, stream>>>(x, x4);
  pack_wt4_kernel<<<dim3(N_DIM / 64, K_DIM / 128), 256, 0, stream>>>(w, w4t);
  gemm_fp4_kernel<<<1024, 256, 0, stream>>>(x4, w4t, out);
}